// Round 2
// baseline (168.387 us; speedup 1.0000x reference)
//
#include <hip/hip_runtime.h>

// Problem constants (PARTViT pairwise head)
#define BB 64
#define NN 576
#define DD 768
#define KK 1024
#define ROWS (BB * NN)    // 36864 patch rows
#define PAIRS (BB * KK)   // 65536 pairs
// d_out layout: [PAIRS*2] f32 head output, then [PAIRS*2] f32 echoed indices

// Per-patch projection table: P[r] = { z[r]·W[:768,0], z[r]·W[:768,1],
//                                      z[r]·W[768:,0], z[r]·W[768:,1] }
// Static device global (576 KB) — avoids any ws_size assumption. Fully
// rewritten by partvit_proj every launch, so graph replay is deterministic.
__device__ float4 g_P[ROWS];

// Kernel 1: one wave per row (grid-stride). Lane l reads float4 #(j*64+l)
// of the row -> covers d = j*256+4l .. +3; matching weights preloaded into
// registers (no LDS, no bank conflicts). 64-lane butterfly reduce.
__global__ __launch_bounds__(256) void partvit_proj(const float* __restrict__ z,
                                                    const float* __restrict__ W) {
    const int lane = threadIdx.x & 63;
    const int wid  = blockIdx.x * (blockDim.x >> 6) + (threadIdx.x >> 6);
    const int nw   = gridDim.x * (blockDim.x >> 6);

    // W is [1536,2] row-major: W[d,t] at 2*d+t -> float2 per d
    const float2* __restrict__ W2 = (const float2*)W;
    float2 wa[3][4], wb[3][4];
#pragma unroll
    for (int j = 0; j < 3; ++j) {
#pragma unroll
        for (int c = 0; c < 4; ++c) {
            const int d = j * 256 + (lane << 2) + c;
            wa[j][c] = W2[d];        // first-half weights (patch-0 slot)
            wb[j][c] = W2[d + 768];  // second-half weights (patch-1 slot)
        }
    }

    const float4* __restrict__ z4 = (const float4*)z;  // 192 float4 per row

    for (int r = wid; r < ROWS; r += nw) {
        float a00 = 0.f, a01 = 0.f, a10 = 0.f, a11 = 0.f;
#pragma unroll
        for (int j = 0; j < 3; ++j) {
            const float4 v = z4[r * 192 + j * 64 + lane];
            a00 = fmaf(v.x, wa[j][0].x, a00);
            a00 = fmaf(v.y, wa[j][1].x, a00);
            a00 = fmaf(v.z, wa[j][2].x, a00);
            a00 = fmaf(v.w, wa[j][3].x, a00);
            a01 = fmaf(v.x, wa[j][0].y, a01);
            a01 = fmaf(v.y, wa[j][1].y, a01);
            a01 = fmaf(v.z, wa[j][2].y, a01);
            a01 = fmaf(v.w, wa[j][3].y, a01);
            a10 = fmaf(v.x, wb[j][0].x, a10);
            a10 = fmaf(v.y, wb[j][1].x, a10);
            a10 = fmaf(v.z, wb[j][2].x, a10);
            a10 = fmaf(v.w, wb[j][3].x, a10);
            a11 = fmaf(v.x, wb[j][0].y, a11);
            a11 = fmaf(v.y, wb[j][1].y, a11);
            a11 = fmaf(v.z, wb[j][2].y, a11);
            a11 = fmaf(v.w, wb[j][3].y, a11);
        }
#pragma unroll
        for (int off = 32; off > 0; off >>= 1) {
            a00 += __shfl_xor(a00, off, 64);
            a01 += __shfl_xor(a01, off, 64);
            a10 += __shfl_xor(a10, off, 64);
            a11 += __shfl_xor(a11, off, 64);
        }
        if (lane == 0) g_P[r] = make_float4(a00, a01, a10, a11);
    }
}

// Kernel 2: per pair: out = P[i0].xy + P[i1].zw + bias ; echo indices as f32.
// Indices clamped to [0, NN-1] so a dtype-contract surprise yields a clean
// absmax failure instead of a memory fault.
__global__ __launch_bounds__(256) void partvit_pairs(const int* __restrict__ idx,
                                                     const float* __restrict__ bh,
                                                     float* __restrict__ out) {
    const int t = blockIdx.x * blockDim.x + threadIdx.x;  // pair id = b*K + k
    if (t >= PAIRS) return;
    const int2 id = ((const int2*)idx)[t];
    const int i0 = min(max(id.x, 0), NN - 1);
    const int i1 = min(max(id.y, 0), NN - 1);
    const int b = t >> 10;  // K = 1024
    const float4 p0 = g_P[b * NN + i0];
    const float4 p1 = g_P[b * NN + i1];
    const float b0 = bh[0], b1 = bh[1];
    ((float2*)out)[t] = make_float2(p0.x + p1.z + b0, p0.y + p1.w + b1);
    ((float2*)out)[PAIRS + t] = make_float2((float)id.x, (float)id.y);
}

extern "C" void kernel_launch(void* const* d_in, const int* in_sizes, int n_in,
                              void* d_out, int out_size, void* d_ws, size_t ws_size,
                              hipStream_t stream) {
    const float* z   = (const float*)d_in[0];
    const int*   idx = (const int*)d_in[1];    // integer input -> int32 per harness contract
    const float* W   = (const float*)d_in[2];
    const float* bh  = (const float*)d_in[3];
    float*       out = (float*)d_out;
    (void)d_ws; (void)ws_size;

    // K1: 1536 blocks * 4 waves = 6144 waves -> 6 rows/wave, ~24 waves/CU
    partvit_proj<<<1536, 256, 0, stream>>>(z, W);
    // K2: one thread per pair
    partvit_pairs<<<PAIRS / 256, 256, 0, stream>>>(idx, bh, out);
}

// Round 4
// 167.985 us; speedup vs baseline: 1.0024x; 1.0024x over previous
//
#include <hip/hip_runtime.h>

// Problem constants (PARTViT pairwise head)
#define BB 64
#define NN 576
#define DD 768
#define KK 1024
#define ROWS (BB * NN)    // 36864 patch rows
#define PAIRS (BB * KK)   // 65536 pairs
// d_out layout: [PAIRS*2] f32 head output, then [PAIRS*2] f32 echoed indices
//
// R3 post-mortem: hipLaunchCooperativeKernel silently fails under the
// harness's graph-capture path (d_out never written). Reverted to the
// proven two-kernel structure from R2 (168.4 µs, absmax 3.9e-3).
// Structural floor of our slice: z read 113 MB @ ~6.5 TB/s ≈ 18 µs (K1)
// + ~3 µs (K2, L2-resident gathers) + 2 launch overheads.

// Per-patch projection table: P[r] = { z[r]·W[:768,0], z[r]·W[:768,1],
//                                      z[r]·W[768:,0], z[r]·W[768:,1] }
// Static device global (576 KB); fully rewritten each launch (replay-safe).
__device__ float4 g_P[ROWS];

// Kernel 1: one wave per row (grid-stride). Lane l reads float4 #(j*64+l)
// of the row -> covers d = j*256+4l .. +3; matching weights preloaded into
// registers (no LDS, no bank conflicts). 64-lane butterfly reduce.
__global__ __launch_bounds__(256) void partvit_proj(const float* __restrict__ z,
                                                    const float* __restrict__ W) {
    const int lane = threadIdx.x & 63;
    const int wid  = blockIdx.x * (blockDim.x >> 6) + (threadIdx.x >> 6);
    const int nw   = gridDim.x * (blockDim.x >> 6);

    // W is [1536,2] row-major: W[d,t] at 2*d+t -> float2 per d
    const float2* __restrict__ W2 = (const float2*)W;
    float2 wa[3][4], wb[3][4];
#pragma unroll
    for (int j = 0; j < 3; ++j) {
#pragma unroll
        for (int c = 0; c < 4; ++c) {
            const int d = j * 256 + (lane << 2) + c;
            wa[j][c] = W2[d];        // first-half weights (patch-0 slot)
            wb[j][c] = W2[d + 768];  // second-half weights (patch-1 slot)
        }
    }

    const float4* __restrict__ z4 = (const float4*)z;  // 192 float4 per row

    for (int r = wid; r < ROWS; r += nw) {
        float a00 = 0.f, a01 = 0.f, a10 = 0.f, a11 = 0.f;
#pragma unroll
        for (int j = 0; j < 3; ++j) {
            const float4 v = z4[r * 192 + j * 64 + lane];
            a00 = fmaf(v.x, wa[j][0].x, a00);
            a00 = fmaf(v.y, wa[j][1].x, a00);
            a00 = fmaf(v.z, wa[j][2].x, a00);
            a00 = fmaf(v.w, wa[j][3].x, a00);
            a01 = fmaf(v.x, wa[j][0].y, a01);
            a01 = fmaf(v.y, wa[j][1].y, a01);
            a01 = fmaf(v.z, wa[j][2].y, a01);
            a01 = fmaf(v.w, wa[j][3].y, a01);
            a10 = fmaf(v.x, wb[j][0].x, a10);
            a10 = fmaf(v.y, wb[j][1].x, a10);
            a10 = fmaf(v.z, wb[j][2].x, a10);
            a10 = fmaf(v.w, wb[j][3].x, a10);
            a11 = fmaf(v.x, wb[j][0].y, a11);
            a11 = fmaf(v.y, wb[j][1].y, a11);
            a11 = fmaf(v.z, wb[j][2].y, a11);
            a11 = fmaf(v.w, wb[j][3].y, a11);
        }
#pragma unroll
        for (int off = 32; off > 0; off >>= 1) {
            a00 += __shfl_xor(a00, off, 64);
            a01 += __shfl_xor(a01, off, 64);
            a10 += __shfl_xor(a10, off, 64);
            a11 += __shfl_xor(a11, off, 64);
        }
        if (lane == 0) g_P[r] = make_float4(a00, a01, a10, a11);
    }
}

// Kernel 2: per pair: out = P[i0].xy + P[i1].zw + bias ; echo indices as f32.
// Indices clamped to [0, NN-1] so a dtype-contract surprise yields a clean
// absmax failure instead of a memory fault.
__global__ __launch_bounds__(256) void partvit_pairs(const int* __restrict__ idx,
                                                     const float* __restrict__ bh,
                                                     float* __restrict__ out) {
    const int t = blockIdx.x * blockDim.x + threadIdx.x;  // pair id = b*K + k
    if (t >= PAIRS) return;
    const int2 id = ((const int2*)idx)[t];
    const int i0 = min(max(id.x, 0), NN - 1);
    const int i1 = min(max(id.y, 0), NN - 1);
    const int b = t >> 10;  // K = 1024
    const float4 p0 = g_P[b * NN + i0];
    const float4 p1 = g_P[b * NN + i1];
    const float b0 = bh[0], b1 = bh[1];
    ((float2*)out)[t] = make_float2(p0.x + p1.z + b0, p0.y + p1.w + b1);
    ((float2*)out)[PAIRS + t] = make_float2((float)id.x, (float)id.y);
}

extern "C" void kernel_launch(void* const* d_in, const int* in_sizes, int n_in,
                              void* d_out, int out_size, void* d_ws, size_t ws_size,
                              hipStream_t stream) {
    const float* z   = (const float*)d_in[0];
    const int*   idx = (const int*)d_in[1];
    const float* W   = (const float*)d_in[2];
    const float* bh  = (const float*)d_in[3];
    float*       out = (float*)d_out;
    (void)d_ws; (void)ws_size;

    // K1: 1536 blocks * 4 waves = 6144 waves -> 6 rows/wave, ~24 waves/CU
    partvit_proj<<<1536, 256, 0, stream>>>(z, W);
    // K2: one thread per pair
    partvit_pairs<<<PAIRS / 256, 256, 0, stream>>>(idx, bh, out);
}